// Round 10
// baseline (263.819 us; speedup 1.0000x reference)
//
#include <hip/hip_runtime.h>
#include <cstddef>

namespace {

constexpr int B = 4, V = 20000, P = 400000, NN = 50000, MP = 32;
constexpr float GAMMA = 10.0f, INV_GAMMA = 0.1f;
constexpr float THRESH = 1.0f;
constexpr float W_WL = 1.0f, W_CONG = 0.5f;
constexpr float KL2 = 2.0f * 1.44269504f;      // K_SOFT * log2(e)
constexpr float HKL2 = 0.5f * KL2;             // 0.5 * K_SOFT * log2(e)
constexpr int BPB = 256;                   // phase-B blocks per batch (3 blocks/CU)
constexpr int NET_GRID = BPB * B;          // 1024 blocks, 4 waves
constexpr int GRPS = 4;                    // up to 64 contiguous nets per wave-stream
constexpr int NPW = GRPS * 16;             // 64
constexpr int A_SUBS = 196;                // phase A: 196*256 = 50176 >= NN
constexpr int A_GRID = A_SUBS * B;

typedef __attribute__((ext_vector_type(8)))  short bf16x8;
typedef __attribute__((ext_vector_type(16))) float f32x16;

__device__ __forceinline__ float fast_rcp(float x) { return __builtin_amdgcn_rcpf(x); }
__device__ __forceinline__ short f2bf(float f) {
    unsigned u = __float_as_uint(f);
    u += 0x7fffu + ((u >> 16) & 1u);
    return (short)(u >> 16);
}
// sigmoid(K(g-lo+.5)) * sigmoid(K(hi-g+.5)) = 1/(1+e1+e2+e1e2).
// R9 BUG: raw exp2f overflow -> inf, other factor -> 0, inf*0 = NaN, and the
// downstream relu swallowed NaN as 0 (lost penalty). Clamp each exp at 1e30:
// both-large is impossible (hi>lo), so the product stays finite and the
// unsaturated region is bit-identical.
__device__ __forceinline__ float sigpair(float loK, float hiK, float gK) {
    float e1 = fminf(exp2f(loK - gK), 1e30f);
    float e2 = fminf(exp2f(gK - hiK), 1e30f);
    return fast_rcp(fmaf(e1, e2, 1.0f + e1 + e2));
}
template <int CTRL>
__device__ __forceinline__ float dpp_mov(float x, float id) {
    return __int_as_float(__builtin_amdgcn_update_dpp(
        __float_as_int(id), __float_as_int(x), CTRL, 0xf, 0xf, false));
}
__device__ __forceinline__ float rdlane(float x, int l) {
    return __int_as_float(__builtin_amdgcn_readlane(__float_as_int(x), l));
}
#define DPP5(x, OP, ID)                              \
    x = OP(x, dpp_mov<0x111>(x, ID));                \
    x = OP(x, dpp_mov<0x112>(x, ID));                \
    x = OP(x, dpp_mov<0x114>(x, ID));                \
    x = OP(x, dpp_mov<0x118>(x, ID));                \
    x = OP(x, dpp_mov<0x142>(x, ID));
__device__ __forceinline__ float op_add(float a, float b) { return a + b; }

__global__ void zero_ws_kernel(float* __restrict__ p, int n) {
    int i = blockIdx.x * blockDim.x + threadIdx.x;
    if (i < n) p[i] = 0.0f;
}

// Fused macro-prep: gather positions + onehot directly per pin.
__global__ void pin_pos_kernel(const float* __restrict__ positions,
                               const float* __restrict__ rot_onehot,
                               const int* __restrict__ pin_to_macro,
                               const float* __restrict__ pin_offsets,
                               float* __restrict__ pin_pos) {
    int idx = blockIdx.x * blockDim.x + threadIdx.x;
    if (idx >= B * P) return;
    int b = idx / P;
    int p = idx - b * P;
    int m = pin_to_macro[p];
    float2 off = ((const float2*)pin_offsets)[p];
    float2 pos = ((const float2*)positions)[(size_t)b * V + m];
    float4 w = ((const float4*)rot_onehot)[(size_t)b * V + m];
    float a = w.x - w.z, c = w.y - w.w;
    ((float2*)pin_pos)[idx] = make_float2(pos.x + a * off.x - c * off.y,
                                          pos.y + c * off.x + a * off.y);
}

__global__ void transpose_n2p_kernel(const int* __restrict__ n2p,
                                     int* __restrict__ n2pT) {
    int i = blockIdx.x * blockDim.x + threadIdx.x;
    if (i >= NN * MP) return;
    int n = i >> 5, j = i & 31;
    n2pT[j * NN + n] = n2p[i];
}

// Phase A: one net per LANE; no cross-lane ops in the pin loop (full MLP).
__global__ void __launch_bounds__(256)
bbox_kernel(const float* __restrict__ pin_pos,
            const int* __restrict__ n2pT,
            const float* __restrict__ net_weights,
            float4* __restrict__ bbox,
            float* __restrict__ hpwl) {
    __shared__ float hps[4];
    int blk = blockIdx.x;
    int xcd = blk & 7;
    int b = xcd >> 1;
    int sub = ((blk >> 3) << 1) | (xcd & 1);
    int tid = threadIdx.x;
    int wave = tid >> 6;
    int lane = tid & 63;

    int n = sub * 256 + wave * 64 + lane;
    bool inrange = n < NN;
    int nc = inrange ? n : (NN - 1);

    const float2* pp = (const float2*)(pin_pos + (size_t)b * P * 2);

    int pi[MP];
    #pragma unroll
    for (int j = 0; j < MP; ++j) pi[j] = n2pT[j * NN + nc];

    float ex1 = 0.f, ex2 = 0.f, ey1 = 0.f, ey2 = 0.f;
    float vxmax = -1e30f, vxmin = 1e30f, vymax = -1e30f, vymin = 1e30f;
    #pragma unroll 8
    for (int j = 0; j < MP; ++j) {
        bool v = pi[j] >= 0;
        float2 q = pp[v ? pi[j] : 0];
        float e1x = __expf(GAMMA * q.x);
        float e1y = __expf(GAMMA * q.y);
        ex1 += v ? e1x : 0.f;
        ex2 += v ? fast_rcp(e1x) : 0.f;
        ey1 += v ? e1y : 0.f;
        ey2 += v ? fast_rcp(e1y) : 0.f;
        vxmax = fmaxf(vxmax, v ? q.x : -1e30f);
        vxmin = fminf(vxmin, v ? q.x :  1e30f);
        vymax = fmaxf(vymax, v ? q.y : -1e30f);
        vymin = fminf(vymin, v ? q.y :  1e30f);
    }
    float w = net_weights[nc];
    float wl = __logf(ex1 * ex2 * ey1 * ey2) * INV_GAMMA;
    float hp = inrange ? wl * w : 0.f;

    if (inrange) {
        bbox[(size_t)b * NN + n] = make_float4(
            (vxmin + 1.0f) * 31.5f, (vxmax + 1.0f) * 31.5f,
            (vymin + 1.0f) * 31.5f, (vymax + 1.0f) * 31.5f);
    }
    DPP5(hp, op_add, 0.0f);
    float tot = rdlane(hp, 31) + rdlane(hp, 63);
    if (lane == 0) hps[wave] = tot;
    __syncthreads();
    if (tid == 0) atomicAdd(&hpwl[b], hps[0] + hps[1] + hps[2] + hps[3]);
}

// Phase B: contiguous 64-net stream per wave, direct per-lane bbox loads
// (L2-hot), lean sigmoid-pair math, rank-16 MFMA. Grid sized for 3 blocks/CU.
__global__ void __launch_bounds__(256)
rudy_kernel(const float4* __restrict__ bbox,
            float* __restrict__ slabs) {   // NET_GRID * 4096
    __shared__ float tile[64 * 65];
    int x = blockIdx.x;
    int xcd = x & 7;
    int b = xcd >> 1;
    int sub = ((x >> 3) << 1) | (xcd & 1);     // 0..BPB-1
    int tid = threadIdx.x;
    int wave = tid >> 6;
    int lane = tid & 63;

    for (int k = tid; k < 64 * 65; k += 256) tile[k] = 0.0f;
    __syncthreads();

    f32x16 acc00, acc01, acc10, acc11;
    #pragma unroll
    for (int r = 0; r < 16; ++r) { acc00[r] = 0.f; acc01[r] = 0.f; acc10[r] = 0.f; acc11[r] = 0.f; }

    int s = sub * 4 + wave;                    // wave-stream id (per batch)
    int s0 = s * NPW;
    const float4* bb_b = bbox + (size_t)b * NN;

    int half8 = (lane >> 5) * 8;               // k-slot base for this half-wave
    float gKa = (float)(lane & 31) * KL2;      // row/col 0..31, pre-scaled
    float gKh = gKa + 32.0f * KL2;             // row/col 32..63

    for (int grp = 0; grp < GRPS; ++grp) {
        int nb0 = s0 + grp * 16;               // wave-uniform
        if (nb0 >= NN) break;
        int nb = nb0 + half8;
        float4 bb[8];
        #pragma unroll
        for (int j = 0; j < 8; ++j) {
            int nt = nb + j;
            bb[j] = bb_b[nt < NN ? nt : NN - 1];
        }
        bf16x8 A0, A1, B0, B1;
        #pragma unroll
        for (int j = 0; j < 8; ++j) {
            float okf = (nb + j < NN) ? 1.0f : 0.0f;
            float4 q = bb[j];
            float xl = fmaf(q.x, KL2, -HKL2);  // (xmin-0.5)*K*log2e
            float xh = fmaf(q.y, KL2,  HKL2);  // (xmax+0.5)*K*log2e
            float yl = fmaf(q.z, KL2, -HKL2);
            float yh = fmaf(q.w, KL2,  HKL2);
            float inv = fast_rcp(fmaxf((q.y - q.x + 1.0f) * (q.w - q.z + 1.0f), 1.0f)) * okf;
            float a0 = sigpair(yl, yh, gKa) * inv;   // A = Y^T rows
            float a1 = sigpair(yl, yh, gKh) * inv;
            float b0 = sigpair(xl, xh, gKa) * okf;   // B = X cols
            float b1 = sigpair(xl, xh, gKh) * okf;
            A0[j] = f2bf(a0); A1[j] = f2bf(a1);
            B0[j] = f2bf(b0); B1[j] = f2bf(b1);
        }
        acc00 = __builtin_amdgcn_mfma_f32_32x32x16_bf16(A0, B0, acc00, 0, 0, 0);
        acc01 = __builtin_amdgcn_mfma_f32_32x32x16_bf16(A0, B1, acc01, 0, 0, 0);
        acc10 = __builtin_amdgcn_mfma_f32_32x32x16_bf16(A1, B0, acc10, 0, 0, 0);
        acc11 = __builtin_amdgcn_mfma_f32_32x32x16_bf16(A1, B1, acc11, 0, 0, 0);
    }

    // C/D layout: col=lane&31, row=(r&3)+8*(r>>2)+4*(lane>>5)  (LDS atomics: intra-block)
    int col = lane & 31, rq = lane >> 5;
    #pragma unroll
    for (int r = 0; r < 16; ++r) {
        int row = (r & 3) + 8 * (r >> 2) + 4 * rq;
        atomicAdd(&tile[row * 65 + col],             acc00[r]);
        atomicAdd(&tile[row * 65 + col + 32],        acc01[r]);
        atomicAdd(&tile[(row + 32) * 65 + col],      acc10[r]);
        atomicAdd(&tile[(row + 32) * 65 + col + 32], acc11[r]);
    }
    __syncthreads();
    float* slab = slabs + ((size_t)b * BPB + sub) * 4096;
    for (int k = tid; k < 4096; k += 256)
        slab[k] = tile[(k >> 6) * 65 + (k & 63)];
}

// Sum BPB slabs -> rudy. XCD-pinned to the pair that wrote the slabs.
__global__ void __launch_bounds__(256)
rudy_reduce_kernel(const float* __restrict__ slabs, float* __restrict__ rudy) {
    int blk = blockIdx.x;                       // 64
    int xcd = blk & 7;
    int b = xcd >> 1;
    int sub = ((blk >> 3) << 1) | (xcd & 1);    // 0..15
    int c = sub * 256 + threadIdx.x;            // cell 0..4095
    const float* base = slabs + (size_t)b * BPB * 4096 + c;
    float a0 = 0.f, a1 = 0.f, a2 = 0.f, a3 = 0.f;
    #pragma unroll 4
    for (int s = 0; s < BPB; s += 4) {
        a0 += base[(size_t)(s + 0) * 4096];
        a1 += base[(size_t)(s + 1) * 4096];
        a2 += base[(size_t)(s + 2) * 4096];
        a3 += base[(size_t)(s + 3) * 4096];
    }
    rudy[b * 4096 + c] = (a0 + a1) + (a2 + a3);
}

__global__ void conv_penalty_kernel(const float* __restrict__ rudy,
                                    float* __restrict__ pen) {
    int blk = blockIdx.x;
    int b = blk >> 4, chunk = blk & 15;
    int r0 = chunk * 4;
    __shared__ float t2[10][64];
    int tid = threadIdx.x;
    for (int k = tid; k < 640; k += 256) {
        int r = k >> 6, c = k & 63, row = r0 - 3 + r;
        t2[r][c] = (row >= 0 && row < 64) ? rudy[b * 4096 + row * 64 + c] : 0.f;
    }
    __syncthreads();
    float g1[7];
    #pragma unroll
    for (int i = 0; i < 7; ++i) { float t = (float)(i - 3); g1[i] = __expf(-t * t / 4.5f); }
    float s1 = g1[0] + g1[1] + g1[2] + g1[3] + g1[4] + g1[5] + g1[6];
    float inv = fast_rcp(s1 * s1);
    int i = tid >> 6, j = tid & 63;
    float acc = 0.f;
    #pragma unroll
    for (int di = -3; di <= 3; ++di) {
        #pragma unroll
        for (int dj = -3; dj <= 3; ++dj) {
            int jj = j + dj;
            float val = (jj >= 0 && jj < 64) ? t2[i + 3 + di][jj] : 0.f;
            acc += g1[di + 3] * g1[dj + 3] * val;
        }
    }
    acc *= inv;
    float ov = acc - THRESH;
    float p = ov > 0.f ? ov * ov : 0.f;
    DPP5(p, op_add, 0.0f);
    float tot = rdlane(p, 31) + rdlane(p, 63);
    if ((tid & 63) == 0) atomicAdd(&pen[b], tot);
}

__global__ void finalize_kernel(const float* __restrict__ hpwl,
                                const float* __restrict__ pen,
                                float* __restrict__ out) {
    int i = threadIdx.x;
    if (i < B) out[i] = W_WL * hpwl[i] + W_CONG * pen[i];
}

} // namespace

extern "C" void kernel_launch(void* const* d_in, const int* in_sizes, int n_in,
                              void* d_out, int out_size, void* d_ws, size_t ws_size,
                              hipStream_t stream) {
    const float* positions    = (const float*)d_in[0];
    const int*   net_to_pin   = (const int*)d_in[1];
    const int*   pin_to_macro = (const int*)d_in[2];
    const float* pin_offsets  = (const float*)d_in[3];
    const float* rot_onehot   = (const float*)d_in[4];
    const float* net_weights  = (const float*)d_in[5];
    float* out = (float*)d_out;

    // ws: pin_pos | rudy | hpwl | pen | bbox | {n2pT / slabs OVERLAY} (~33 MB)
    // n2pT is dead after bbox_kernel; slabs (written later in stream) reuse it.
    float*  pin_pos = (float*)d_ws;
    float*  rudy    = pin_pos + (size_t)B * P * 2;
    float*  hpwl    = rudy + (size_t)B * 64 * 64;
    float*  pen     = hpwl + B;
    float4* bboxb   = (float4*)(pen + B);
    float*  shared_region = (float*)(bboxb + (size_t)B * NN);
    int*    n2pT    = (int*)shared_region;                 // 6.4 MB
    float*  slabs   = shared_region;                       // 16.8 MB (overlay)

    zero_ws_kernel<<<1, 64, 0, stream>>>(hpwl, 2 * B);
    pin_pos_kernel<<<(B * P + 255) / 256, 256, 0, stream>>>(
        positions, rot_onehot, pin_to_macro, pin_offsets, pin_pos);
    transpose_n2p_kernel<<<(NN * MP + 255) / 256, 256, 0, stream>>>(net_to_pin, n2pT);
    bbox_kernel<<<A_GRID, 256, 0, stream>>>(pin_pos, n2pT, net_weights, bboxb, hpwl);
    rudy_kernel<<<NET_GRID, 256, 0, stream>>>(bboxb, slabs);
    rudy_reduce_kernel<<<64, 256, 0, stream>>>(slabs, rudy);
    conv_penalty_kernel<<<64, 256, 0, stream>>>(rudy, pen);
    finalize_kernel<<<1, 64, 0, stream>>>(hpwl, pen, out);
}

// Round 11
// 226.964 us; speedup vs baseline: 1.1624x; 1.1624x over previous
//
#include <hip/hip_runtime.h>
#include <cstddef>

namespace {

constexpr int B = 4, V = 20000, P = 400000, NN = 50000, MP = 32;
constexpr float GAMMA = 10.0f, INV_GAMMA = 0.1f;
constexpr float KS = 2.0f;                 // K_SOFT (natural-exp domain; __expf is fast v_exp)
constexpr float THRESH = 1.0f;
constexpr float W_WL = 1.0f, W_CONG = 0.5f;
constexpr int BPB = 192;                   // phase-B blocks per batch -> 768 blocks = 3/CU
constexpr int NET_GRID = BPB * B;
constexpr int GRPS = 5;                    // 80 contiguous nets per wave-stream
constexpr int NPW = GRPS * 16;             // 80;  192*4*80 = 61440 >= NN
constexpr int A_SUBS = 196;                // phase A: 196*256 = 50176 >= NN
constexpr int A_GRID = A_SUBS * B;

typedef __attribute__((ext_vector_type(8)))  short bf16x8;
typedef __attribute__((ext_vector_type(16))) float f32x16;

__device__ __forceinline__ float fast_rcp(float x) { return __builtin_amdgcn_rcpf(x); }
__device__ __forceinline__ short f2bf(float f) {
    unsigned u = __float_as_uint(f);
    u += 0x7fffu + ((u >> 16) & 1u);
    return (short)(u >> 16);
}
// sigmoid(K(g-lo+.5)) * sigmoid(K(hi-g+.5)) = 1/(1+e1+e2+e1e2), e1=e^{K(lo-.5-g)},
// e2=e^{K(g-hi-.5)}. __expf = fast v_exp (R10 regression: plain exp2f w/o fast-math
// is the slow accurate libm path). Clamp at 1e30: overflow->inf would meet the other
// factor's 0 as inf*0=NaN, silently swallowed by the downstream relu (R9 bug).
__device__ __forceinline__ float sigpair(float a1, float a2) {
    float e1 = fminf(__expf(a1), 1e30f);
    float e2 = fminf(__expf(a2), 1e30f);
    return fast_rcp(fmaf(e1, e2, 1.0f + e1 + e2));
}
template <int CTRL>
__device__ __forceinline__ float dpp_mov(float x, float id) {
    return __int_as_float(__builtin_amdgcn_update_dpp(
        __float_as_int(id), __float_as_int(x), CTRL, 0xf, 0xf, false));
}
__device__ __forceinline__ float rdlane(float x, int l) {
    return __int_as_float(__builtin_amdgcn_readlane(__float_as_int(x), l));
}
#define DPP5(x, OP, ID)                              \
    x = OP(x, dpp_mov<0x111>(x, ID));                \
    x = OP(x, dpp_mov<0x112>(x, ID));                \
    x = OP(x, dpp_mov<0x114>(x, ID));                \
    x = OP(x, dpp_mov<0x118>(x, ID));                \
    x = OP(x, dpp_mov<0x142>(x, ID));
__device__ __forceinline__ float op_add(float a, float b) { return a + b; }

__global__ void zero_ws_kernel(float* __restrict__ p, int n) {
    int i = blockIdx.x * blockDim.x + threadIdx.x;
    if (i < n) p[i] = 0.0f;
}

// One thread per PIN, loop over the 4 batches: index/offset loads amortized 4x.
__global__ void pin_pos_kernel(const float* __restrict__ positions,
                               const float* __restrict__ rot_onehot,
                               const int* __restrict__ pin_to_macro,
                               const float* __restrict__ pin_offsets,
                               float* __restrict__ pin_pos) {
    int p = blockIdx.x * blockDim.x + threadIdx.x;
    if (p >= P) return;
    int m = pin_to_macro[p];
    float2 off = ((const float2*)pin_offsets)[p];
    #pragma unroll
    for (int b = 0; b < B; ++b) {
        float2 pos = ((const float2*)positions)[(size_t)b * V + m];
        float4 w = ((const float4*)rot_onehot)[(size_t)b * V + m];
        float a = w.x - w.z, c = w.y - w.w;
        ((float2*)pin_pos)[(size_t)b * P + p] =
            make_float2(pos.x + a * off.x - c * off.y,
                        pos.y + c * off.x + a * off.y);
    }
}

__global__ void transpose_n2p_kernel(const int* __restrict__ n2p,
                                     int* __restrict__ n2pT) {
    int i = blockIdx.x * blockDim.x + threadIdx.x;
    if (i >= NN * MP) return;
    int n = i >> 5, j = i & 31;
    n2pT[j * NN + n] = n2p[i];
}

// Phase A: one net per LANE; no cross-lane ops in the pin loop (full MLP).
__global__ void __launch_bounds__(256)
bbox_kernel(const float* __restrict__ pin_pos,
            const int* __restrict__ n2pT,
            const float* __restrict__ net_weights,
            float4* __restrict__ bbox,
            float* __restrict__ hpwl) {
    __shared__ float hps[4];
    int blk = blockIdx.x;
    int xcd = blk & 7;
    int b = xcd >> 1;
    int sub = ((blk >> 3) << 1) | (xcd & 1);
    int tid = threadIdx.x;
    int wave = tid >> 6;
    int lane = tid & 63;

    int n = sub * 256 + wave * 64 + lane;
    bool inrange = n < NN;
    int nc = inrange ? n : (NN - 1);

    const float2* pp = (const float2*)(pin_pos + (size_t)b * P * 2);

    int pi[MP];
    #pragma unroll
    for (int j = 0; j < MP; ++j) pi[j] = n2pT[j * NN + nc];

    float ex1 = 0.f, ex2 = 0.f, ey1 = 0.f, ey2 = 0.f;
    float vxmax = -1e30f, vxmin = 1e30f, vymax = -1e30f, vymin = 1e30f;
    #pragma unroll 8
    for (int j = 0; j < MP; ++j) {
        bool v = pi[j] >= 0;
        float2 q = pp[v ? pi[j] : 0];
        float e1x = __expf(GAMMA * q.x);
        float e1y = __expf(GAMMA * q.y);
        ex1 += v ? e1x : 0.f;
        ex2 += v ? fast_rcp(e1x) : 0.f;
        ey1 += v ? e1y : 0.f;
        ey2 += v ? fast_rcp(e1y) : 0.f;
        vxmax = fmaxf(vxmax, v ? q.x : -1e30f);
        vxmin = fminf(vxmin, v ? q.x :  1e30f);
        vymax = fmaxf(vymax, v ? q.y : -1e30f);
        vymin = fminf(vymin, v ? q.y :  1e30f);
    }
    float w = net_weights[nc];
    float wl = __logf(ex1 * ex2 * ey1 * ey2) * INV_GAMMA;
    float hp = inrange ? wl * w : 0.f;

    if (inrange) {
        bbox[(size_t)b * NN + n] = make_float4(
            (vxmin + 1.0f) * 31.5f, (vxmax + 1.0f) * 31.5f,
            (vymin + 1.0f) * 31.5f, (vymax + 1.0f) * 31.5f);
    }
    DPP5(hp, op_add, 0.0f);
    float tot = rdlane(hp, 31) + rdlane(hp, 63);
    if (lane == 0) hps[wave] = tot;
    __syncthreads();
    if (tid == 0) atomicAdd(&hpwl[b], hps[0] + hps[1] + hps[2] + hps[3]);
}

// Phase B: contiguous 80-net stream per wave, direct per-lane bbox loads
// (L2-hot), fast-exp fused sigmoid pairs, rank-16 MFMA. 768 blocks = 3/CU.
__global__ void __launch_bounds__(256)
rudy_kernel(const float4* __restrict__ bbox,
            float* __restrict__ slabs) {   // NET_GRID * 4096
    __shared__ float tile[64 * 65];
    int x = blockIdx.x;
    int xcd = x & 7;
    int b = xcd >> 1;
    int sub = ((x >> 3) << 1) | (xcd & 1);     // 0..BPB-1
    int tid = threadIdx.x;
    int wave = tid >> 6;
    int lane = tid & 63;

    for (int k = tid; k < 64 * 65; k += 256) tile[k] = 0.0f;
    __syncthreads();

    f32x16 acc00, acc01, acc10, acc11;
    #pragma unroll
    for (int r = 0; r < 16; ++r) { acc00[r] = 0.f; acc01[r] = 0.f; acc10[r] = 0.f; acc11[r] = 0.f; }

    int s = sub * 4 + wave;                    // wave-stream id (per batch)
    int s0 = s * NPW;
    const float4* bb_b = bbox + (size_t)b * NN;

    int half8 = (lane >> 5) * 8;               // k-slot base for this half-wave
    float gK = (float)(lane & 31) * KS;        // K*g for rows/cols 0..31
    float gKh = gK + 32.0f * KS;               // K*g for rows/cols 32..63

    for (int grp = 0; grp < GRPS; ++grp) {
        int nb0 = s0 + grp * 16;               // wave-uniform
        if (nb0 >= NN) break;
        int nb = nb0 + half8;
        float4 bb[8];
        #pragma unroll
        for (int j = 0; j < 8; ++j) {
            int nt = nb + j;
            bb[j] = bb_b[nt < NN ? nt : NN - 1];
        }
        bf16x8 A0, A1, B0, B1;
        #pragma unroll
        for (int j = 0; j < 8; ++j) {
            float okf = (nb + j < NN) ? 1.0f : 0.0f;
            float4 q = bb[j];
            float xl = fmaf(q.x, KS, -0.5f * KS);   // K*(xmin-0.5)
            float xh = fmaf(q.y, KS,  0.5f * KS);   // K*(xmax+0.5)
            float yl = fmaf(q.z, KS, -0.5f * KS);
            float yh = fmaf(q.w, KS,  0.5f * KS);
            float inv = fast_rcp(fmaxf((q.y - q.x + 1.0f) * (q.w - q.z + 1.0f), 1.0f)) * okf;
            float a0 = sigpair(yl - gK,  gK  - yh) * inv;   // A = Y^T rows
            float a1 = sigpair(yl - gKh, gKh - yh) * inv;
            float b0 = sigpair(xl - gK,  gK  - xh) * okf;   // B = X cols
            float b1 = sigpair(xl - gKh, gKh - xh) * okf;
            A0[j] = f2bf(a0); A1[j] = f2bf(a1);
            B0[j] = f2bf(b0); B1[j] = f2bf(b1);
        }
        acc00 = __builtin_amdgcn_mfma_f32_32x32x16_bf16(A0, B0, acc00, 0, 0, 0);
        acc01 = __builtin_amdgcn_mfma_f32_32x32x16_bf16(A0, B1, acc01, 0, 0, 0);
        acc10 = __builtin_amdgcn_mfma_f32_32x32x16_bf16(A1, B0, acc10, 0, 0, 0);
        acc11 = __builtin_amdgcn_mfma_f32_32x32x16_bf16(A1, B1, acc11, 0, 0, 0);
    }

    // C/D layout: col=lane&31, row=(r&3)+8*(r>>2)+4*(lane>>5)  (LDS atomics: intra-block)
    int col = lane & 31, rq = lane >> 5;
    #pragma unroll
    for (int r = 0; r < 16; ++r) {
        int row = (r & 3) + 8 * (r >> 2) + 4 * rq;
        atomicAdd(&tile[row * 65 + col],             acc00[r]);
        atomicAdd(&tile[row * 65 + col + 32],        acc01[r]);
        atomicAdd(&tile[(row + 32) * 65 + col],      acc10[r]);
        atomicAdd(&tile[(row + 32) * 65 + col + 32], acc11[r]);
    }
    __syncthreads();
    float* slab = slabs + ((size_t)b * BPB + sub) * 4096;
    for (int k = tid; k < 4096; k += 256)
        slab[k] = tile[(k >> 6) * 65 + (k & 63)];
}

// Sum BPB slabs -> rudy. XCD-pinned to the pair that wrote the slabs.
__global__ void __launch_bounds__(256)
rudy_reduce_kernel(const float* __restrict__ slabs, float* __restrict__ rudy) {
    int blk = blockIdx.x;                       // 64
    int xcd = blk & 7;
    int b = xcd >> 1;
    int sub = ((blk >> 3) << 1) | (xcd & 1);    // 0..15
    int c = sub * 256 + threadIdx.x;            // cell 0..4095
    const float* base = slabs + (size_t)b * BPB * 4096 + c;
    float a0 = 0.f, a1 = 0.f, a2 = 0.f, a3 = 0.f;
    #pragma unroll 4
    for (int s = 0; s < BPB; s += 4) {
        a0 += base[(size_t)(s + 0) * 4096];
        a1 += base[(size_t)(s + 1) * 4096];
        a2 += base[(size_t)(s + 2) * 4096];
        a3 += base[(size_t)(s + 3) * 4096];
    }
    rudy[b * 4096 + c] = (a0 + a1) + (a2 + a3);
}

__global__ void conv_penalty_kernel(const float* __restrict__ rudy,
                                    float* __restrict__ pen) {
    int blk = blockIdx.x;
    int b = blk >> 4, chunk = blk & 15;
    int r0 = chunk * 4;
    __shared__ float t2[10][64];
    int tid = threadIdx.x;
    for (int k = tid; k < 640; k += 256) {
        int r = k >> 6, c = k & 63, row = r0 - 3 + r;
        t2[r][c] = (row >= 0 && row < 64) ? rudy[b * 4096 + row * 64 + c] : 0.f;
    }
    __syncthreads();
    float g1[7];
    #pragma unroll
    for (int i = 0; i < 7; ++i) { float t = (float)(i - 3); g1[i] = __expf(-t * t / 4.5f); }
    float s1 = g1[0] + g1[1] + g1[2] + g1[3] + g1[4] + g1[5] + g1[6];
    float inv = fast_rcp(s1 * s1);
    int i = tid >> 6, j = tid & 63;
    float acc = 0.f;
    #pragma unroll
    for (int di = -3; di <= 3; ++di) {
        #pragma unroll
        for (int dj = -3; dj <= 3; ++dj) {
            int jj = j + dj;
            float val = (jj >= 0 && jj < 64) ? t2[i + 3 + di][jj] : 0.f;
            acc += g1[di + 3] * g1[dj + 3] * val;
        }
    }
    acc *= inv;
    float ov = acc - THRESH;
    float p = ov > 0.f ? ov * ov : 0.f;
    DPP5(p, op_add, 0.0f);
    float tot = rdlane(p, 31) + rdlane(p, 63);
    if ((tid & 63) == 0) atomicAdd(&pen[b], tot);
}

__global__ void finalize_kernel(const float* __restrict__ hpwl,
                                const float* __restrict__ pen,
                                float* __restrict__ out) {
    int i = threadIdx.x;
    if (i < B) out[i] = W_WL * hpwl[i] + W_CONG * pen[i];
}

} // namespace

extern "C" void kernel_launch(void* const* d_in, const int* in_sizes, int n_in,
                              void* d_out, int out_size, void* d_ws, size_t ws_size,
                              hipStream_t stream) {
    const float* positions    = (const float*)d_in[0];
    const int*   net_to_pin   = (const int*)d_in[1];
    const int*   pin_to_macro = (const int*)d_in[2];
    const float* pin_offsets  = (const float*)d_in[3];
    const float* rot_onehot   = (const float*)d_in[4];
    const float* net_weights  = (const float*)d_in[5];
    float* out = (float*)d_out;

    // ws: pin_pos | rudy | hpwl | pen | bbox | {n2pT / slabs OVERLAY} (~29 MB)
    float*  pin_pos = (float*)d_ws;
    float*  rudy    = pin_pos + (size_t)B * P * 2;
    float*  hpwl    = rudy + (size_t)B * 64 * 64;
    float*  pen     = hpwl + B;
    float4* bboxb   = (float4*)(pen + B);
    float*  shared_region = (float*)(bboxb + (size_t)B * NN);
    int*    n2pT    = (int*)shared_region;                 // 6.4 MB (dead after bbox)
    float*  slabs   = shared_region;                       // 12.6 MB (overlay)

    zero_ws_kernel<<<1, 64, 0, stream>>>(hpwl, 2 * B);
    pin_pos_kernel<<<(P + 255) / 256, 256, 0, stream>>>(
        positions, rot_onehot, pin_to_macro, pin_offsets, pin_pos);
    transpose_n2p_kernel<<<(NN * MP + 255) / 256, 256, 0, stream>>>(net_to_pin, n2pT);
    bbox_kernel<<<A_GRID, 256, 0, stream>>>(pin_pos, n2pT, net_weights, bboxb, hpwl);
    rudy_kernel<<<NET_GRID, 256, 0, stream>>>(bboxb, slabs);
    rudy_reduce_kernel<<<64, 256, 0, stream>>>(slabs, rudy);
    conv_penalty_kernel<<<64, 256, 0, stream>>>(rudy, pen);
    finalize_kernel<<<1, 64, 0, stream>>>(hpwl, pen, out);
}

// Round 12
// 205.491 us; speedup vs baseline: 1.2838x; 1.1045x over previous
//
#include <hip/hip_runtime.h>
#include <cstddef>

namespace {

constexpr int B = 4, V = 20000, P = 400000, NN = 50000, MP = 32;
constexpr float GAMMA = 10.0f, INV_GAMMA = 0.1f;
constexpr float KS = 2.0f;                 // K_SOFT
constexpr float THRESH = 1.0f;
constexpr float W_WL = 1.0f, W_CONG = 0.5f;
constexpr int BPB = 128;                   // phase-B blocks per batch (R12: back to R7's minimum grid —
constexpr int NET_GRID = BPB * B;          //  wall scales with block count; 512 blocks measured best)
constexpr int GRPS = 7;                    // 112 contiguous nets per wave-stream
constexpr int NPW = GRPS * 16;             // 112
constexpr int A_SUBS = 196;                // phase A: 196*256 = 50176 >= NN
constexpr int A_GRID = A_SUBS * B;

typedef __attribute__((ext_vector_type(8)))  short bf16x8;
typedef __attribute__((ext_vector_type(16))) float f32x16;

__device__ __forceinline__ float fast_rcp(float x) { return __builtin_amdgcn_rcpf(x); }
__device__ __forceinline__ short f2bf(float f) {
    unsigned u = __float_as_uint(f);
    u += 0x7fffu + ((u >> 16) & 1u);
    return (short)(u >> 16);
}
// sigmoid(K(g-lo+.5)) * sigmoid(K(hi-g+.5)) = 1/(1+e1+e2+e1e2), e1=e^{K(lo-.5-g)},
// e2=e^{K(g-hi-.5)}. __expf = fast v_exp. Clamp at 1e30: overflow->inf would meet
// the other factor's 0 as inf*0=NaN, silently swallowed by downstream relu (R9 bug).
__device__ __forceinline__ float sigpair(float a1, float a2) {
    float e1 = fminf(__expf(a1), 1e30f);
    float e2 = fminf(__expf(a2), 1e30f);
    return fast_rcp(fmaf(e1, e2, 1.0f + e1 + e2));
}
template <int CTRL>
__device__ __forceinline__ float dpp_mov(float x, float id) {
    return __int_as_float(__builtin_amdgcn_update_dpp(
        __float_as_int(id), __float_as_int(x), CTRL, 0xf, 0xf, false));
}
__device__ __forceinline__ float rdlane(float x, int l) {
    return __int_as_float(__builtin_amdgcn_readlane(__float_as_int(x), l));
}
#define DPP5(x, OP, ID)                              \
    x = OP(x, dpp_mov<0x111>(x, ID));                \
    x = OP(x, dpp_mov<0x112>(x, ID));                \
    x = OP(x, dpp_mov<0x114>(x, ID));                \
    x = OP(x, dpp_mov<0x118>(x, ID));                \
    x = OP(x, dpp_mov<0x142>(x, ID));
__device__ __forceinline__ float op_add(float a, float b) { return a + b; }

__global__ void zero_ws_kernel(float* __restrict__ p, int n) {
    int i = blockIdx.x * blockDim.x + threadIdx.x;
    if (i < n) p[i] = 0.0f;
}

// One thread per PIN, loop over the 4 batches: index/offset loads amortized 4x.
__global__ void pin_pos_kernel(const float* __restrict__ positions,
                               const float* __restrict__ rot_onehot,
                               const int* __restrict__ pin_to_macro,
                               const float* __restrict__ pin_offsets,
                               float* __restrict__ pin_pos) {
    int p = blockIdx.x * blockDim.x + threadIdx.x;
    if (p >= P) return;
    int m = pin_to_macro[p];
    float2 off = ((const float2*)pin_offsets)[p];
    #pragma unroll
    for (int b = 0; b < B; ++b) {
        float2 pos = ((const float2*)positions)[(size_t)b * V + m];
        float4 w = ((const float4*)rot_onehot)[(size_t)b * V + m];
        float a = w.x - w.z, c = w.y - w.w;
        ((float2*)pin_pos)[(size_t)b * P + p] =
            make_float2(pos.x + a * off.x - c * off.y,
                        pos.y + c * off.x + a * off.y);
    }
}

__global__ void transpose_n2p_kernel(const int* __restrict__ n2p,
                                     int* __restrict__ n2pT) {
    int i = blockIdx.x * blockDim.x + threadIdx.x;
    if (i >= NN * MP) return;
    int n = i >> 5, j = i & 31;
    n2pT[j * NN + n] = n2p[i];
}

// Phase A: one net per LANE; no cross-lane ops in the pin loop (full MLP).
__global__ void __launch_bounds__(256)
bbox_kernel(const float* __restrict__ pin_pos,
            const int* __restrict__ n2pT,
            const float* __restrict__ net_weights,
            float4* __restrict__ bbox,
            float* __restrict__ hpwl) {
    __shared__ float hps[4];
    int blk = blockIdx.x;
    int xcd = blk & 7;
    int b = xcd >> 1;
    int sub = ((blk >> 3) << 1) | (xcd & 1);
    int tid = threadIdx.x;
    int wave = tid >> 6;
    int lane = tid & 63;

    int n = sub * 256 + wave * 64 + lane;
    bool inrange = n < NN;
    int nc = inrange ? n : (NN - 1);

    const float2* pp = (const float2*)(pin_pos + (size_t)b * P * 2);

    int pi[MP];
    #pragma unroll
    for (int j = 0; j < MP; ++j) pi[j] = n2pT[j * NN + nc];

    float ex1 = 0.f, ex2 = 0.f, ey1 = 0.f, ey2 = 0.f;
    float vxmax = -1e30f, vxmin = 1e30f, vymax = -1e30f, vymin = 1e30f;
    #pragma unroll 8
    for (int j = 0; j < MP; ++j) {
        bool v = pi[j] >= 0;
        float2 q = pp[v ? pi[j] : 0];
        float e1x = __expf(GAMMA * q.x);
        float e1y = __expf(GAMMA * q.y);
        ex1 += v ? e1x : 0.f;
        ex2 += v ? fast_rcp(e1x) : 0.f;
        ey1 += v ? e1y : 0.f;
        ey2 += v ? fast_rcp(e1y) : 0.f;
        vxmax = fmaxf(vxmax, v ? q.x : -1e30f);
        vxmin = fminf(vxmin, v ? q.x :  1e30f);
        vymax = fmaxf(vymax, v ? q.y : -1e30f);
        vymin = fminf(vymin, v ? q.y :  1e30f);
    }
    float w = net_weights[nc];
    float wl = __logf(ex1 * ex2 * ey1 * ey2) * INV_GAMMA;
    float hp = inrange ? wl * w : 0.f;

    if (inrange) {
        bbox[(size_t)b * NN + n] = make_float4(
            (vxmin + 1.0f) * 31.5f, (vxmax + 1.0f) * 31.5f,
            (vymin + 1.0f) * 31.5f, (vymax + 1.0f) * 31.5f);
    }
    DPP5(hp, op_add, 0.0f);
    float tot = rdlane(hp, 31) + rdlane(hp, 63);
    if (lane == 0) hps[wave] = tot;
    __syncthreads();
    if (tid == 0) atomicAdd(&hpwl[b], hps[0] + hps[1] + hps[2] + hps[3]);
}

// Phase B: R7 structure (512 blocks, 112-net streams, direct per-lane bbox
// loads) + R11's 3-transcendental sigpair. Minimum grid measured fastest —
// wall tracks block count, extra occupancy doesn't hide the per-wave stall.
__global__ void __launch_bounds__(256)
rudy_kernel(const float4* __restrict__ bbox,
            float* __restrict__ slabs) {   // NET_GRID * 4096
    __shared__ float tile[64 * 65];
    int x = blockIdx.x;
    int xcd = x & 7;
    int b = xcd >> 1;
    int sub = ((x >> 3) << 1) | (xcd & 1);     // 0..BPB-1
    int tid = threadIdx.x;
    int wave = tid >> 6;
    int lane = tid & 63;

    for (int k = tid; k < 64 * 65; k += 256) tile[k] = 0.0f;
    __syncthreads();

    f32x16 acc00, acc01, acc10, acc11;
    #pragma unroll
    for (int r = 0; r < 16; ++r) { acc00[r] = 0.f; acc01[r] = 0.f; acc10[r] = 0.f; acc11[r] = 0.f; }

    int s = sub * 4 + wave;                    // wave-stream id (per batch)
    int s0 = s * NPW;
    const float4* bb_b = bbox + (size_t)b * NN;

    int half8 = (lane >> 5) * 8;               // k-slot base for this half-wave
    float gK = (float)(lane & 31) * KS;        // K*g for rows/cols 0..31
    float gKh = gK + 32.0f * KS;               // K*g for rows/cols 32..63

    if (s0 < NN) {
        for (int grp = 0; grp < GRPS; ++grp) {
            int nb0 = s0 + grp * 16;           // wave-uniform
            if (nb0 >= NN) break;
            int nb = nb0 + half8;
            float4 bb[8];
            #pragma unroll
            for (int j = 0; j < 8; ++j) {
                int nt = nb + j;
                bb[j] = bb_b[nt < NN ? nt : NN - 1];
            }
            bf16x8 A0, A1, B0, B1;
            #pragma unroll
            for (int j = 0; j < 8; ++j) {
                float okf = (nb + j < NN) ? 1.0f : 0.0f;
                float4 q = bb[j];
                float xl = fmaf(q.x, KS, -0.5f * KS);   // K*(xmin-0.5)
                float xh = fmaf(q.y, KS,  0.5f * KS);   // K*(xmax+0.5)
                float yl = fmaf(q.z, KS, -0.5f * KS);
                float yh = fmaf(q.w, KS,  0.5f * KS);
                float inv = fast_rcp(fmaxf((q.y - q.x + 1.0f) * (q.w - q.z + 1.0f), 1.0f)) * okf;
                float a0 = sigpair(yl - gK,  gK  - yh) * inv;   // A = Y^T rows
                float a1 = sigpair(yl - gKh, gKh - yh) * inv;
                float b0 = sigpair(xl - gK,  gK  - xh) * okf;   // B = X cols
                float b1 = sigpair(xl - gKh, gKh - xh) * okf;
                A0[j] = f2bf(a0); A1[j] = f2bf(a1);
                B0[j] = f2bf(b0); B1[j] = f2bf(b1);
            }
            acc00 = __builtin_amdgcn_mfma_f32_32x32x16_bf16(A0, B0, acc00, 0, 0, 0);
            acc01 = __builtin_amdgcn_mfma_f32_32x32x16_bf16(A0, B1, acc01, 0, 0, 0);
            acc10 = __builtin_amdgcn_mfma_f32_32x32x16_bf16(A1, B0, acc10, 0, 0, 0);
            acc11 = __builtin_amdgcn_mfma_f32_32x32x16_bf16(A1, B1, acc11, 0, 0, 0);
        }
    }

    // C/D layout: col=lane&31, row=(r&3)+8*(r>>2)+4*(lane>>5)  (LDS atomics: intra-block)
    int col = lane & 31, rq = lane >> 5;
    #pragma unroll
    for (int r = 0; r < 16; ++r) {
        int row = (r & 3) + 8 * (r >> 2) + 4 * rq;
        atomicAdd(&tile[row * 65 + col],             acc00[r]);
        atomicAdd(&tile[row * 65 + col + 32],        acc01[r]);
        atomicAdd(&tile[(row + 32) * 65 + col],      acc10[r]);
        atomicAdd(&tile[(row + 32) * 65 + col + 32], acc11[r]);
    }
    __syncthreads();
    float* slab = slabs + ((size_t)b * BPB + sub) * 4096;
    for (int k = tid; k < 4096; k += 256)
        slab[k] = tile[(k >> 6) * 65 + (k & 63)];
}

// Sum BPB slabs -> rudy. XCD-pinned to the pair that wrote the slabs.
__global__ void __launch_bounds__(256)
rudy_reduce_kernel(const float* __restrict__ slabs, float* __restrict__ rudy) {
    int blk = blockIdx.x;                       // 64
    int xcd = blk & 7;
    int b = xcd >> 1;
    int sub = ((blk >> 3) << 1) | (xcd & 1);    // 0..15
    int c = sub * 256 + threadIdx.x;            // cell 0..4095
    const float* base = slabs + (size_t)b * BPB * 4096 + c;
    float a0 = 0.f, a1 = 0.f, a2 = 0.f, a3 = 0.f;
    #pragma unroll 4
    for (int s = 0; s < BPB; s += 4) {
        a0 += base[(size_t)(s + 0) * 4096];
        a1 += base[(size_t)(s + 1) * 4096];
        a2 += base[(size_t)(s + 2) * 4096];
        a3 += base[(size_t)(s + 3) * 4096];
    }
    rudy[b * 4096 + c] = (a0 + a1) + (a2 + a3);
}

__global__ void conv_penalty_kernel(const float* __restrict__ rudy,
                                    float* __restrict__ pen) {
    int blk = blockIdx.x;
    int b = blk >> 4, chunk = blk & 15;
    int r0 = chunk * 4;
    __shared__ float t2[10][64];
    int tid = threadIdx.x;
    for (int k = tid; k < 640; k += 256) {
        int r = k >> 6, c = k & 63, row = r0 - 3 + r;
        t2[r][c] = (row >= 0 && row < 64) ? rudy[b * 4096 + row * 64 + c] : 0.f;
    }
    __syncthreads();
    float g1[7];
    #pragma unroll
    for (int i = 0; i < 7; ++i) { float t = (float)(i - 3); g1[i] = __expf(-t * t / 4.5f); }
    float s1 = g1[0] + g1[1] + g1[2] + g1[3] + g1[4] + g1[5] + g1[6];
    float inv = fast_rcp(s1 * s1);
    int i = tid >> 6, j = tid & 63;
    float acc = 0.f;
    #pragma unroll
    for (int di = -3; di <= 3; ++di) {
        #pragma unroll
        for (int dj = -3; dj <= 3; ++dj) {
            int jj = j + dj;
            float val = (jj >= 0 && jj < 64) ? t2[i + 3 + di][jj] : 0.f;
            acc += g1[di + 3] * g1[dj + 3] * val;
        }
    }
    acc *= inv;
    float ov = acc - THRESH;
    float p = ov > 0.f ? ov * ov : 0.f;
    DPP5(p, op_add, 0.0f);
    float tot = rdlane(p, 31) + rdlane(p, 63);
    if ((tid & 63) == 0) atomicAdd(&pen[b], tot);
}

__global__ void finalize_kernel(const float* __restrict__ hpwl,
                                const float* __restrict__ pen,
                                float* __restrict__ out) {
    int i = threadIdx.x;
    if (i < B) out[i] = W_WL * hpwl[i] + W_CONG * pen[i];
}

} // namespace

extern "C" void kernel_launch(void* const* d_in, const int* in_sizes, int n_in,
                              void* d_out, int out_size, void* d_ws, size_t ws_size,
                              hipStream_t stream) {
    const float* positions    = (const float*)d_in[0];
    const int*   net_to_pin   = (const int*)d_in[1];
    const int*   pin_to_macro = (const int*)d_in[2];
    const float* pin_offsets  = (const float*)d_in[3];
    const float* rot_onehot   = (const float*)d_in[4];
    const float* net_weights  = (const float*)d_in[5];
    float* out = (float*)d_out;

    // ws: pin_pos | rudy | hpwl | pen | bbox | {n2pT / slabs OVERLAY} (~25 MB)
    float*  pin_pos = (float*)d_ws;
    float*  rudy    = pin_pos + (size_t)B * P * 2;
    float*  hpwl    = rudy + (size_t)B * 64 * 64;
    float*  pen     = hpwl + B;
    float4* bboxb   = (float4*)(pen + B);
    float*  shared_region = (float*)(bboxb + (size_t)B * NN);
    int*    n2pT    = (int*)shared_region;                 // 6.4 MB (dead after bbox)
    float*  slabs   = shared_region;                       // 8.4 MB (overlay)

    zero_ws_kernel<<<1, 64, 0, stream>>>(hpwl, 2 * B);
    pin_pos_kernel<<<(P + 255) / 256, 256, 0, stream>>>(
        positions, rot_onehot, pin_to_macro, pin_offsets, pin_pos);
    transpose_n2p_kernel<<<(NN * MP + 255) / 256, 256, 0, stream>>>(net_to_pin, n2pT);
    bbox_kernel<<<A_GRID, 256, 0, stream>>>(pin_pos, n2pT, net_weights, bboxb, hpwl);
    rudy_kernel<<<NET_GRID, 256, 0, stream>>>(bboxb, slabs);
    rudy_reduce_kernel<<<64, 256, 0, stream>>>(slabs, rudy);
    conv_penalty_kernel<<<64, 256, 0, stream>>>(rudy, pen);
    finalize_kernel<<<1, 64, 0, stream>>>(hpwl, pen, out);
}